// Round 13
// baseline (753.224 us; speedup 1.0000x reference)
//
#include <hip/hip_runtime.h>
#include <cstdint>
#include <cstddef>

#define NN 20000      // nodes
#define NE 640000     // edges
#define DD 128        // feature dim
#define NP 10000      // products (output cols)
#define NRT 1250      // NN/16 row-tiles
#define NRT_PAD 1256  // padded rt16 (= 314 row-tiles of 64)
#define NCT_PAD 632   // padded col-tiles of 16 (79 panels of 128)
#define NWG_BIG 474   // 6 row-splits x 79 col panels

typedef __attribute__((ext_vector_type(8))) short short8;
typedef __attribute__((ext_vector_type(4))) float f32x4;

static __device__ __forceinline__ unsigned short f2bf(float f){
  uint32_t u = __float_as_uint(f);
  return (unsigned short)((u + 0x7fffu + ((u >> 16) & 1u)) >> 16);
}
static __device__ __forceinline__ float bf2f(unsigned short u){
  return __uint_as_float(((uint32_t)u) << 16);
}

static __device__ __forceinline__ void gload_lds16(const void* g, void* l){
  __builtin_amdgcn_global_load_lds(
      (const __attribute__((address_space(1))) void*)g,
      (__attribute__((address_space(3))) void*)l, 16, 0, 0);
}

// ---------------- prologue: count + all weight packers ----------------
// block ranges: [0,5000) count | [5000,5256) wfrag4 | [5256,7784) wfrag2
#define PREP_NWG 7784
__global__ __launch_bounds__(256) void k_prep(
    const int* __restrict__ dst_u, const int* __restrict__ dst_p, int* __restrict__ cnt,
    const float* __restrict__ uW, const float* __restrict__ pW,
    unsigned short* __restrict__ WuF0, unsigned short* __restrict__ WuF1,
    unsigned short* __restrict__ WpF0, unsigned short* __restrict__ WpF1,
    const float* __restrict__ oW, unsigned short* __restrict__ WoF){
  __shared__ float tile[32][33];
  const int b = blockIdx.x, tid = threadIdx.x;

  if (b < 5000){                      // degree count, both graphs
    int i = b * 256 + tid;
    if (i < NE) atomicAdd(&cnt[dst_u[i]], 1);
    else atomicAdd(&cnt[NN + dst_p[i - NE]], 1);

  } else if (b < 5256){               // 4 small conv weights -> frag order
    int bw = b - 5000;
    int wy = bw >> 6, bx = bw & 63;
    const float* W; unsigned short* Wf;
    switch (wy){
      case 0: W = uW;                   Wf = WuF0; break;
      case 1: W = uW + (size_t)DD * DD; Wf = WuF1; break;
      case 2: W = pW;                   Wf = WpF0; break;
      default:W = pW + (size_t)DD * DD; Wf = WpF1; break;
    }
    int i = bx * 256 + tid;
    int e = i & 7, l = (i >> 3) & 63, rem = i >> 9;
    int kt = rem & 3, ct = rem >> 2;
    int col = ct * 16 + (l & 15);
    int k = kt * 32 + (l >> 4) * 8 + e;
    Wf[i] = f2bf(W[(size_t)k * DD + col]);

  } else {                            // big weight oW [256][NP] -> frag order (LDS transpose)
    int bw = b - 5256;
    int bx = bw % 316, by = bw / 316;
    const int kb = by * 32, cb = bx * 32;
    const int tx = tid & 31, ty = tid >> 5;
    const int col = cb + tx;
    #pragma unroll
    for (int j = 0; j < 4; j++){
      int k = ty + j * 8;
      tile[k][tx] = (col < NP) ? oW[(size_t)(kb + k) * NP + col] : 0.f;
    }
    __syncthreads();
    const int ct2 = tid >> 7, rep = tid & 1, l = (tid >> 1) & 63;
    const int c_loc = ct2 * 16 + (l & 15);
    const int k_loc = (l >> 4) * 8 + rep * 4;
    ushort4 o;
    o.x = f2bf(tile[k_loc + 0][c_loc]);
    o.y = f2bf(tile[k_loc + 1][c_loc]);
    o.z = f2bf(tile[k_loc + 2][c_loc]);
    o.w = f2bf(tile[k_loc + 3][c_loc]);
    const int ct = cb / 16 + ct2, kt = kb / 32;
    *reinterpret_cast<ushort4*>(WoF + ((size_t)(ct * 8 + kt) * 64 + l) * 8 + rep * 4) = o;
  }
}

// ---------------- scan (+dinv fused): 2 blocks, block g scans graph g ----------------
__global__ void k_scan2(const int* __restrict__ cnt, int* __restrict__ row_off,
                        int* __restrict__ cursor, float* __restrict__ dinv){
  __shared__ int part[1024];
  const int g = blockIdx.x;
  const int* c = cnt + g * NN;
  int* ro = row_off + g * (NN + 1);
  int* cur = cursor + g * NN;
  float* dv = dinv + g * NN;
  int t = threadIdx.x;
  int per = (NN + 1023) >> 10;
  int base = t * per;
  int s = 0;
  for (int i = 0; i < per; i++){
    int idx = base + i;
    if (idx < NN){
      int cv = c[idx];
      dv[idx] = rsqrtf((float)(cv + 1));   // +1 self-loop
      s += cv;
    }
  }
  part[t] = s;
  __syncthreads();
  for (int off = 1; off < 1024; off <<= 1){
    int v = (t >= off) ? part[t - off] : 0;
    __syncthreads();
    part[t] += v;
    __syncthreads();
  }
  int run = (t == 0) ? 0 : part[t - 1];
  for (int i = 0; i < per; i++){
    int idx = base + i;
    if (idx < NN){ ro[idx] = run; cur[idx] = run; run += c[idx]; }
  }
  if (t == 0) ro[NN] = part[1023];
}

__global__ void k_fill2(const int* __restrict__ src_u, const int* __restrict__ dst_u,
                        const int* __restrict__ src_p, const int* __restrict__ dst_p,
                        int* __restrict__ cursor, int* __restrict__ col){ // col[2*NE]
  int i = blockIdx.x * blockDim.x + threadIdx.x;
  if (i < NE){
    int p = atomicAdd(&cursor[dst_u[i]], 1);
    col[p] = src_u[i];
  } else if (i < 2 * NE){
    int j = i - NE;
    int p = atomicAdd(&cursor[NN + dst_p[j]], 1);
    col[NE + p] = src_p[j];
  }
}

// ---------------- fused layer 1: embedding gather (LDS frags) + conv ----------------
// grid (313, 2); block = 4 waves = 4 node-tiles (64 nodes).
__global__ __launch_bounds__(256) void k_l1(
    const float* __restrict__ utab, const int* __restrict__ uids,
    const float* __restrict__ ptab, const int* __restrict__ pids,
    const unsigned short* __restrict__ Wu, const unsigned short* __restrict__ Wp,
    const float* __restrict__ du, const float* __restrict__ dp,
    unsigned short* __restrict__ hu, unsigned short* __restrict__ hp){
  __shared__ unsigned short af[4 * 4 * 64 * 8];   // 16 KB A-fragments
  const int g = blockIdx.y;
  const float* tab = g ? ptab : utab;
  const int*   ids = g ? pids : uids;
  const unsigned short* Wf = g ? Wp : Wu;
  const float* dinv = g ? dp : du;
  unsigned short* hsb = g ? hp : hu;

  const int tid = threadIdx.x;
  const int tx = tid & 31, ny = tid >> 5;       // tx: dim-quad (d = tx*4..+3)
  const int nbase = blockIdx.x * 64;
  #pragma unroll
  for (int rep = 0; rep < 8; rep++){
    int nl = ny + rep * 8;                      // node_local 0..63
    int node = nbase + nl;
    int id = ids[min(node, NN - 1)];
    const float4 v = *reinterpret_cast<const float4*>(tab + (size_t)id * DD + tx * 4);
    ushort4 o; o.x = f2bf(v.x); o.y = f2bf(v.y); o.z = f2bf(v.z); o.w = f2bf(v.w);
    int chunk = ((nl >> 4) * 4 + (tx >> 3)) * 64 + ((tx >> 1) & 3) * 16 + (nl & 15);
    *reinterpret_cast<ushort4*>(af + chunk * 8 + (tx & 1) * 4) = o;
  }
  __syncthreads();

  const int wid = tid >> 6, lane = tid & 63;
  const int gw = blockIdx.x * 4 + wid;
  const bool valid = gw < NRT;
  short8 a[4];
  #pragma unroll
  for (int kt = 0; kt < 4; kt++)
    a[kt] = *reinterpret_cast<const short8*>(af + ((wid * 4 + kt) * 64 + lane) * 8);
  const int fr = lane & 15, fq = lane >> 4;
  #pragma unroll
  for (int ct = 0; ct < 8; ct++){
    f32x4 acc = {0.f, 0.f, 0.f, 0.f};
    #pragma unroll
    for (int kt = 0; kt < 4; kt++){
      short8 b = *reinterpret_cast<const short8*>(Wf + ((size_t)(ct * 4 + kt) * 64 + lane) * 8);
      acc = __builtin_amdgcn_mfma_f32_16x16x32_bf16(a[kt], b, acc, 0, 0, 0);
    }
    if (valid){
      #pragma unroll
      for (int r = 0; r < 4; r++){
        int grow = gw * 16 + fq * 4 + r;
        hsb[(size_t)grow * DD + ct * 16 + fr] = f2bf(dinv[grow] * acc[r]);
      }
    }
  }
}

// ---------------- fused layer 2: agg (LDS frags) + conv ----------------
// grid (313, 2); agg phase: 4 subtiles x (16 nodes x 16 lanes); conv phase as k_l1.
__global__ __launch_bounds__(256) void k_l2(
    const unsigned short* __restrict__ hu, const unsigned short* __restrict__ hp,
    const float* __restrict__ du, const float* __restrict__ dp,
    const int* __restrict__ ro, const int* __restrict__ colb,
    const float* __restrict__ bu, const float* __restrict__ bp,
    const unsigned short* __restrict__ Wu, const unsigned short* __restrict__ Wp,
    unsigned short* __restrict__ hu2, unsigned short* __restrict__ hp2){
  __shared__ unsigned short af[4 * 4 * 64 * 8];   // 16 KB A-fragments
  const int g = blockIdx.y;
  const unsigned short* hin = g ? hp : hu;
  const float* dv   = g ? dp : du;
  const float* bias = g ? bp : bu;
  const unsigned short* Wf = g ? Wp : Wu;
  unsigned short* hout = g ? hp2 : hu2;
  const int* row_off = ro + g * (NN + 1);
  const int* col     = colb + (size_t)g * NE;

  const int tid = threadIdx.x;
  const int tx = tid & 15, nsub = tid >> 4;       // 16 lanes per node
  const short8* h8 = reinterpret_cast<const short8*>(hin);
  for (int s = 0; s < 4; s++){
    const int nl = s * 16 + nsub;
    const int node = blockIdx.x * 64 + nl;
    if (node < NN){
      float a[8];
      {
        short8 v = h8[(size_t)node * 16 + tx];
        #pragma unroll
        for (int j = 0; j < 8; j++) a[j] = bf2f((unsigned short)v[j]);
      }
      int st = row_off[node], e = row_off[node + 1];
      int i = st;
      for (; i + 3 < e; i += 4){
        short8 v0 = h8[(size_t)col[i] * 16 + tx];
        short8 v1 = h8[(size_t)col[i + 1] * 16 + tx];
        short8 v2 = h8[(size_t)col[i + 2] * 16 + tx];
        short8 v3 = h8[(size_t)col[i + 3] * 16 + tx];
        #pragma unroll
        for (int j = 0; j < 8; j++)
          a[j] += (bf2f((unsigned short)v0[j]) + bf2f((unsigned short)v1[j]))
                + (bf2f((unsigned short)v2[j]) + bf2f((unsigned short)v3[j]));
      }
      for (; i < e; i++){
        short8 v = h8[(size_t)col[i] * 16 + tx];
        #pragma unroll
        for (int j = 0; j < 8; j++) a[j] += bf2f((unsigned short)v[j]);
      }
      const float dn = dv[node];
      short8 ov;
      #pragma unroll
      for (int j = 0; j < 8; j++)
        ov[j] = (short)f2bf(dn * a[j] + bias[tx * 8 + j]);
      // kt = tx>>2, k8 = tx&3, fr = nl&15
      int chunk = (s * 4 + (tx >> 2)) * 64 + (tx & 3) * 16 + (nl & 15);
      *reinterpret_cast<short8*>(af + chunk * 8) = ov;
    }
  }
  __syncthreads();

  const int wid = tid >> 6, lane = tid & 63;
  const int gw = blockIdx.x * 4 + wid;
  const bool valid = gw < NRT;
  short8 a[4];
  #pragma unroll
  for (int kt = 0; kt < 4; kt++)
    a[kt] = *reinterpret_cast<const short8*>(af + ((wid * 4 + kt) * 64 + lane) * 8);
  const int fr = lane & 15, fq = lane >> 4;
  #pragma unroll
  for (int ct = 0; ct < 8; ct++){
    f32x4 acc = {0.f, 0.f, 0.f, 0.f};
    #pragma unroll
    for (int kt = 0; kt < 4; kt++){
      short8 b = *reinterpret_cast<const short8*>(Wf + ((size_t)(ct * 4 + kt) * 64 + lane) * 8);
      acc = __builtin_amdgcn_mfma_f32_16x16x32_bf16(a[kt], b, acc, 0, 0, 0);
    }
    if (valid){
      #pragma unroll
      for (int r = 0; r < 4; r++){
        int grow = gw * 16 + fq * 4 + r;
        hout[(size_t)grow * DD + ct * 16 + fr] = f2bf(dv[grow] * acc[r]);
      }
    }
  }
}

// ---------------- aggregation layer 2 (bf16 hs2) -> comb frag bf16 ----------------
__global__ void k_agg2(const unsigned short* __restrict__ hu, const unsigned short* __restrict__ hp,
                       const float* __restrict__ du, const float* __restrict__ dp,
                       const int* __restrict__ ro, const int* __restrict__ colb,
                       const float* __restrict__ bu, const float* __restrict__ bp,
                       unsigned short* __restrict__ xfu, unsigned short* __restrict__ xfp,
                       int KT, int toff_p){
  const int g = blockIdx.y;
  const unsigned short* hsb = g ? hp : hu;
  const float* dv   = g ? dp : du;
  const float* bias = g ? bp : bu;
  unsigned short* xf = g ? xfp : xfu;
  const int* row_off = ro + g * (NN + 1);
  const int* col     = colb + (size_t)g * NE;
  const int toff = g ? toff_p : 0;

  int node = blockIdx.x * blockDim.y + threadIdx.y;
  int tx = threadIdx.x;   // 0..15; dims tx*8..tx*8+7
  if (node >= NN) return;
  const short8* h8 = reinterpret_cast<const short8*>(hsb);
  float a[8];
  {
    short8 v = h8[(size_t)node * 16 + tx];
    #pragma unroll
    for (int j = 0; j < 8; j++) a[j] = bf2f((unsigned short)v[j]);
  }
  int s = row_off[node], e = row_off[node + 1];
  int i = s;
  for (; i + 3 < e; i += 4){
    short8 v0 = h8[(size_t)col[i] * 16 + tx];
    short8 v1 = h8[(size_t)col[i + 1] * 16 + tx];
    short8 v2 = h8[(size_t)col[i + 2] * 16 + tx];
    short8 v3 = h8[(size_t)col[i + 3] * 16 + tx];
    #pragma unroll
    for (int j = 0; j < 8; j++)
      a[j] += (bf2f((unsigned short)v0[j]) + bf2f((unsigned short)v1[j]))
            + (bf2f((unsigned short)v2[j]) + bf2f((unsigned short)v3[j]));
  }
  for (; i < e; i++){
    short8 v = h8[(size_t)col[i] * 16 + tx];
    #pragma unroll
    for (int j = 0; j < 8; j++) a[j] += bf2f((unsigned short)v[j]);
  }
  float dn = dv[node];
  short8 ov;
  #pragma unroll
  for (int j = 0; j < 8; j++)
    ov[j] = (short)f2bf(dn * a[j] + bias[tx * 8 + j]);
  size_t chunk = ((size_t)(node >> 4) * KT + toff + (tx >> 2)) * 64 + (tx & 3) * 16 + (node & 15);
  *reinterpret_cast<short8*>(xf + chunk * 8) = ov;
}

// ---------------- rowsum pass: row-stationary, A-in-regs, ZERO atomics ----------------
// grid 314 blocks x 4 waves; wave owns 16 rows (A frag in 64 VGPR).
// Loops 158 B-panels of 64 cols (32 KB LDS dbuf). Per-lane partial sum-of-exp
// accumulated in regs across all panels; one shuffle-reduce + plain store at end.
__global__ __launch_bounds__(256, 2) void k_rsum(
    const unsigned short* __restrict__ Af, const unsigned short* __restrict__ Bf,
    const float* __restrict__ ob, float* __restrict__ rowsum){
  __shared__ unsigned short sB[2][16384];   // 2 x 32 KB
  const int tid = threadIdx.x, lane = tid & 63, wid = tid >> 6;
  const int fr = lane & 15, fq = lane >> 4;
  const int rt16 = blockIdx.x * 4 + wid;    // 16-row tile, 0..1255

  short8 a[8];
  #pragma unroll
  for (int kt = 0; kt < 8; kt++)
    a[kt] = *reinterpret_cast<const short8*>(Af + (((size_t)rt16 * 8 + kt) * 64 + lane) * 8);

  float rs[4] = {0.f, 0.f, 0.f, 0.f};

#define STAGEB(buf, pc) do{                                                    \
    _Pragma("unroll")                                                          \
    for (int i_ = 0; i_ < 8; i_++){                                            \
      int c_ = i_ * 256 + tid;                                                 \
      gload_lds16(Bf + ((size_t)(pc) * 2048 + c_) * 8, (void*)&sB[buf][c_ * 8]); \
    } }while(0)

  STAGEB(0, 0);
  for (int pc = 0; pc < 158; pc++){
    const int p = pc & 1;
    if (pc + 1 < 158){
      STAGEB(p ^ 1, pc + 1);
      asm volatile("s_waitcnt vmcnt(8)" ::: "memory");
    } else {
      asm volatile("s_waitcnt vmcnt(0)" ::: "memory");
    }
    __builtin_amdgcn_s_barrier();

    f32x4 acc[4];
    __builtin_amdgcn_s_setprio(1);
    #pragma unroll
    for (int n = 0; n < 4; n++){
      acc[n] = (f32x4){0.f, 0.f, 0.f, 0.f};
      #pragma unroll
      for (int kt = 0; kt < 8; kt++){
        short8 b = *reinterpret_cast<const short8*>(&sB[p][((n * 8 + kt) * 64 + lane) * 8]);
        acc[n] = __builtin_amdgcn_mfma_f32_16x16x32_bf16(a[kt], b, acc[n], 0, 0, 0);
      }
    }
    __builtin_amdgcn_s_setprio(0);
    __builtin_amdgcn_s_barrier();

    #pragma unroll
    for (int n = 0; n < 4; n++){
      const int gcol = pc * 64 + n * 16 + fr;
      if (gcol < NP){
        const float obv = ob[gcol];
        #pragma unroll
        for (int r = 0; r < 4; r++)
          rs[r] += __expf(acc[n][r] + obv);
      }
    }
  }
#undef STAGEB

  #pragma unroll
  for (int r = 0; r < 4; r++){
    float v = rs[r];
    v += __shfl_xor(v, 1, 64);
    v += __shfl_xor(v, 2, 64);
    v += __shfl_xor(v, 4, 64);
    v += __shfl_xor(v, 8, 64);
    if (fr == 0){
      int grow = rt16 * 16 + fq * 4 + r;
      if (grow < NN) rowsum[grow] = v;
    }
  }
}

// ---------------- big GEMM pass1: B-stationary, B-in-regs, A via LDS dbuf ----------------
// grid 474 = 6 row-splits x 79 col-panels, 256 thr, 2 blocks/CU.
// out = exp(z)/rowsum, full-line nt stores.
__global__ __launch_bounds__(256, 2) void k_big(
    const unsigned short* __restrict__ Af, const unsigned short* __restrict__ Bf,
    const float* __restrict__ ob, const float* __restrict__ rowsum,
    float* __restrict__ out){
  __shared__ unsigned short sA[2][16384];   // 2 x 32KB (one 64-row x 256-K tile)
  const int tid = threadIdx.x, lane = tid & 63, wid = tid >> 6;
  const int wm = wid >> 1, wn = wid & 1;
  const int fr = lane & 15, fq = lane >> 4;

  // bijective XCD chunking: 474 = 8*59 + 2
  const int orig = blockIdx.x;
  const int xcd = orig & 7, pos = orig >> 3;
  const int wgid = (xcd < 2 ? xcd * 60 : 120 + (xcd - 2) * 59) + pos;
  const int six = wgid / 79, cp = wgid - six * 79;
  const int rt0 = six * 52 + (six < 2 ? six : 2);     // row-tile-of-64 start
  const int nrt = 52 + (six < 2 ? 1 : 0);             // 53,53,52,52,52,52 -> 314
  const int bct = cp * 8;

  short8 breg[4][8];
  #pragma unroll
  for (int n = 0; n < 4; n++)
    #pragma unroll
    for (int kt = 0; kt < 8; kt++)
      breg[n][kt] = *reinterpret_cast<const short8*>(
          Bf + (((size_t)(bct + wn * 4 + n) * 8 + kt) * 64 + lane) * 8);

  float obv[4];
  #pragma unroll
  for (int n = 0; n < 4; n++){
    int gcol = cp * 128 + wn * 64 + n * 16 + fr;
    obv[n] = (gcol < NP) ? ob[gcol] : 0.f;
  }

#define STAGEA(buf, rt) do{                                                    \
    _Pragma("unroll")                                                          \
    for (int i_ = 0; i_ < 8; i_++){                                            \
      int c_ = i_ * 256 + tid;                                                 \
      gload_lds16(Af + ((size_t)(rt) * 2048 + c_) * 8, (void*)&sA[buf][c_ * 8]); \
    } }while(0)

  STAGEA(0, rt0);
  for (int t = 0; t < nrt; t++){
    const int p = t & 1;
    if (t + 1 < nrt){
      STAGEA(p ^ 1, rt0 + t + 1);
      asm volatile("s_waitcnt vmcnt(8)" ::: "memory");
    } else {
      asm volatile("s_waitcnt vmcnt(0)" ::: "memory");
    }
    __builtin_amdgcn_s_barrier();

    f32x4 acc[2][4] = {};
    __builtin_amdgcn_s_setprio(1);
    #pragma unroll
    for (int m = 0; m < 2; m++)
      #pragma unroll
      for (int kt = 0; kt < 8; kt++){
        short8 a = *reinterpret_cast<const short8*>(
            &sA[p][(((wm * 2 + m) * 8 + kt) * 64 + lane) * 8]);
        #pragma unroll
        for (int n = 0; n < 4; n++)
          acc[m][n] = __builtin_amdgcn_mfma_f32_16x16x32_bf16(a, breg[n][kt], acc[m][n], 0, 0, 0);
      }
    __builtin_amdgcn_s_setprio(0);
    __builtin_amdgcn_s_barrier();

    const int rbase = (rt0 + t) * 64 + wm * 32;
    #pragma unroll
    for (int m = 0; m < 2; m++)
      #pragma unroll
      for (int r = 0; r < 4; r++){
        const int grow = rbase + m * 16 + fq * 4 + r;
        const bool rv = grow < NN;
        const float ri = rv ? 1.f / rowsum[grow] : 0.f;
        #pragma unroll
        for (int n = 0; n < 4; n++){
          const int gcol = cp * 128 + wn * 64 + n * 16 + fr;
          if (rv && gcol < NP)
            __builtin_nontemporal_store(ri * __expf(acc[m][n][r] + obv[n]),
                                        &out[(size_t)grow * NP + gcol]);
        }
      }
  }
#undef STAGEA
}

// ---------------- host ----------------
extern "C" void kernel_launch(void* const* d_in, const int* in_sizes, int n_in,
                              void* d_out, int out_size, void* d_ws, size_t ws_size,
                              hipStream_t stream){
  const int*   user_ids = (const int*)d_in[0];
  const int*   prod_ids = (const int*)d_in[1];
  const int*   ei_u     = (const int*)d_in[2];
  const int*   ei_p     = (const int*)d_in[3];
  const float* utab     = (const float*)d_in[4];
  const float* ptab     = (const float*)d_in[5];
  const float* uW       = (const float*)d_in[6];
  const float* ub       = (const float*)d_in[7];
  const float* pW       = (const float*)d_in[8];
  const float* pb       = (const float*)d_in[9];
  const float* oW       = (const float*)d_in[10];
  const float* ob       = (const float*)d_in[11];
  float* out = (float*)d_out;
  (void)in_sizes; (void)n_in; (void)out_size; (void)ws_size;

  char* w = (char*)d_ws;
  size_t off = 0;
  auto alloc = [&](size_t bytes)->void*{
    void* p = w + off; off += (bytes + 255) & ~(size_t)255; return p;
  };
  int*   cnt    = (int*)alloc(2 * NN * 4);
  float* rowsum = (float*)alloc(NN * 4);
  float* dinv   = (float*)alloc(2 * NN * 4);     // [u | p]
  int*   ro     = (int*)alloc(2 * (NN + 1) * 4); // [u | p]
  int*   cur    = (int*)alloc(2 * NN * 4);
  int*   colb   = (int*)alloc((size_t)2 * NE * 4);
  unsigned short* comb_f= (unsigned short*)alloc((size_t)NRT_PAD * 8 * 64 * 8 * 2);
  unsigned short* hu    = (unsigned short*)alloc((size_t)NN * DD * 2);
  unsigned short* hp    = (unsigned short*)alloc((size_t)NN * DD * 2);
  unsigned short* hu2   = (unsigned short*)alloc((size_t)NN * DD * 2);
  unsigned short* hp2   = (unsigned short*)alloc((size_t)NN * DD * 2);
  unsigned short* WuF0 = (unsigned short*)alloc((size_t)DD * DD * 2);
  unsigned short* WuF1 = (unsigned short*)alloc((size_t)DD * DD * 2);
  unsigned short* WpF0 = (unsigned short*)alloc((size_t)DD * DD * 2);
  unsigned short* WpF1 = (unsigned short*)alloc((size_t)DD * DD * 2);
  unsigned short* WoF  = (unsigned short*)alloc((size_t)NCT_PAD * 8 * 64 * 8 * 2);

  hipMemsetAsync(cnt, 0, 2 * NN * 4, stream);    // cnt only (rowsum is direct-stored now)
  hipMemsetAsync(comb_f + (size_t)NRT * 8 * 64 * 8, 0,
                 (size_t)(NRT_PAD - NRT) * 8 * 64 * 8 * 2, stream);  // pad rows only

  const int* src_u = ei_u;  const int* dst_u = ei_u + NE;
  const int* src_p = ei_p;  const int* dst_p = ei_p + NE;

  k_prep<<<PREP_NWG, 256, 0, stream>>>(dst_u, dst_p, cnt,
                                       uW, pW, WuF0, WuF1, WpF0, WpF1, oW, WoF);
  k_scan2<<<2, 1024, 0, stream>>>(cnt, ro, cur, dinv);
  k_fill2<<<(2 * NE + 255) / 256, 256, 0, stream>>>(src_u, dst_u, src_p, dst_p, cur, colb);

  const int convGrid = (NRT + 3) / 4;   // 313

  // fused layer 1: gather + conv1
  k_l1<<<dim3(convGrid, 2), 256, 0, stream>>>(utab, user_ids, ptab, prod_ids,
                                              WuF0, WpF0, dinv, dinv + NN, hu, hp);
  // fused layer 2: agg1 + conv2
  k_l2<<<dim3(convGrid, 2), 256, 0, stream>>>(hu, hp, dinv, dinv + NN, ro, colb,
                                              ub, pb, WuF1, WpF1, hu2, hp2);
  // agg2 -> comb fragments (user ktiles 0..3, product ktiles 4..7)
  dim3 aggBlk(16, 16);
  k_agg2<<<dim3((NN + 15) / 16, 2), aggBlk, 0, stream>>>(hu2, hp2, dinv, dinv + NN, ro, colb,
                                                         ub + DD, pb + DD, comb_f, comb_f, 8, 4);

  // rowsum pass (row-stationary, no atomics), then output pass
  k_rsum<<<NRT_PAD / 4, 256, 0, stream>>>(comb_f, WoF, ob, rowsum);
  k_big<<<NWG_BIG, 256, 0, stream>>>(comb_f, WoF, ob, rowsum, out);
}

// Round 14
// 703.123 us; speedup vs baseline: 1.0713x; 1.0713x over previous
//
#include <hip/hip_runtime.h>
#include <cstdint>
#include <cstddef>

#define NN 20000      // nodes
#define NE 640000     // edges
#define DD 128        // feature dim
#define NP 10000      // products (output cols)
#define NRT 1250      // NN/16 row-tiles
#define NRT_PAD 1256  // padded rt16 (= 314 row-tiles of 64)
#define NCT_PAD 632   // padded col-tiles of 16 (79 panels of 128)
#define NWG_BIG 474   // 79 col panels x 6 row-range blocks

typedef __attribute__((ext_vector_type(8))) short short8;
typedef __attribute__((ext_vector_type(4))) float f32x4;

static __device__ __forceinline__ unsigned short f2bf(float f){
  uint32_t u = __float_as_uint(f);
  return (unsigned short)((u + 0x7fffu + ((u >> 16) & 1u)) >> 16);
}
static __device__ __forceinline__ float bf2f(unsigned short u){
  return __uint_as_float(((uint32_t)u) << 16);
}

static __device__ __forceinline__ void gload_lds16(const void* g, void* l){
  __builtin_amdgcn_global_load_lds(
      (const __attribute__((address_space(1))) void*)g,
      (__attribute__((address_space(3))) void*)l, 16, 0, 0);
}

// ---------------- mega-prologue: count + gather(frag) + all weight packers ----------------
// block ranges: [0,5000) count | [5000,10000) gather | [10000,10256) wfrag4 | [10256,12784) wfrag2
#define PREP_NWG 12784
__global__ __launch_bounds__(256) void k_prep(
    const int* __restrict__ dst_u, const int* __restrict__ dst_p, int* __restrict__ cnt,
    const float* __restrict__ utab, const int* __restrict__ uids,
    const float* __restrict__ ptab, const int* __restrict__ pids,
    unsigned short* __restrict__ xu, unsigned short* __restrict__ xp,
    const float* __restrict__ uW, const float* __restrict__ pW,
    unsigned short* __restrict__ WuF0, unsigned short* __restrict__ WuF1,
    unsigned short* __restrict__ WpF0, unsigned short* __restrict__ WpF1,
    const float* __restrict__ oW, unsigned short* __restrict__ WoF){
  __shared__ float tile[32][33];
  const int b = blockIdx.x, tid = threadIdx.x;

  if (b < 5000){                      // degree count, both graphs
    int i = b * 256 + tid;
    if (i < NE) atomicAdd(&cnt[dst_u[i]], 1);
    else atomicAdd(&cnt[NN + dst_p[i - NE]], 1);

  } else if (b < 10000){              // embedding gather -> frag order
    int bg = b - 5000;
    int tower = bg / 2500, nb = bg % 2500;
    const float* tab = tower ? ptab : utab;
    const int*   ids = tower ? pids : uids;
    unsigned short* xf = tower ? xp : xu;
    int tx = tid & 31, ny = tid >> 5;
    int node = nb * 8 + ny;
    const float4 v = *reinterpret_cast<const float4*>(tab + (size_t)ids[node] * DD + tx * 4);
    ushort4 o; o.x = f2bf(v.x); o.y = f2bf(v.y); o.z = f2bf(v.z); o.w = f2bf(v.w);
    size_t chunk = ((size_t)(node >> 4) * 4 + (tx >> 3)) * 64 + ((tx >> 1) & 3) * 16 + (node & 15);
    *reinterpret_cast<ushort4*>(xf + chunk * 8 + (tx & 1) * 4) = o;

  } else if (b < 10256){              // 4 small conv weights -> frag order
    int bw = b - 10000;
    int wy = bw >> 6, bx = bw & 63;
    const float* W; unsigned short* Wf;
    switch (wy){
      case 0: W = uW;                   Wf = WuF0; break;
      case 1: W = uW + (size_t)DD * DD; Wf = WuF1; break;
      case 2: W = pW;                   Wf = WpF0; break;
      default:W = pW + (size_t)DD * DD; Wf = WpF1; break;
    }
    int i = bx * 256 + tid;
    int e = i & 7, l = (i >> 3) & 63, rem = i >> 9;
    int kt = rem & 3, ct = rem >> 2;
    int col = ct * 16 + (l & 15);
    int k = kt * 32 + (l >> 4) * 8 + e;
    Wf[i] = f2bf(W[(size_t)k * DD + col]);

  } else {                            // big weight oW [256][NP] -> frag order (LDS transpose)
    int bw = b - 10256;
    int bx = bw % 316, by = bw / 316;
    const int kb = by * 32, cb = bx * 32;
    const int tx = tid & 31, ty = tid >> 5;
    const int col = cb + tx;
    #pragma unroll
    for (int j = 0; j < 4; j++){
      int k = ty + j * 8;
      tile[k][tx] = (col < NP) ? oW[(size_t)(kb + k) * NP + col] : 0.f;
    }
    __syncthreads();
    const int ct2 = tid >> 7, rep = tid & 1, l = (tid >> 1) & 63;
    const int c_loc = ct2 * 16 + (l & 15);
    const int k_loc = (l >> 4) * 8 + rep * 4;
    ushort4 o;
    o.x = f2bf(tile[k_loc + 0][c_loc]);
    o.y = f2bf(tile[k_loc + 1][c_loc]);
    o.z = f2bf(tile[k_loc + 2][c_loc]);
    o.w = f2bf(tile[k_loc + 3][c_loc]);
    const int ct = cb / 16 + ct2, kt = kb / 32;
    *reinterpret_cast<ushort4*>(WoF + ((size_t)(ct * 8 + kt) * 64 + l) * 8 + rep * 4) = o;
  }
}

// ---------------- scan (+dinv fused): 2 blocks, block g scans graph g ----------------
__global__ void k_scan2(const int* __restrict__ cnt, int* __restrict__ row_off,
                        int* __restrict__ cursor, float* __restrict__ dinv){
  __shared__ int part[1024];
  const int g = blockIdx.x;
  const int* c = cnt + g * NN;
  int* ro = row_off + g * (NN + 1);
  int* cur = cursor + g * NN;
  float* dv = dinv + g * NN;
  int t = threadIdx.x;
  int per = (NN + 1023) >> 10;
  int base = t * per;
  int s = 0;
  for (int i = 0; i < per; i++){
    int idx = base + i;
    if (idx < NN){
      int cv = c[idx];
      dv[idx] = rsqrtf((float)(cv + 1));   // +1 self-loop
      s += cv;
    }
  }
  part[t] = s;
  __syncthreads();
  for (int off = 1; off < 1024; off <<= 1){
    int v = (t >= off) ? part[t - off] : 0;
    __syncthreads();
    part[t] += v;
    __syncthreads();
  }
  int run = (t == 0) ? 0 : part[t - 1];
  for (int i = 0; i < per; i++){
    int idx = base + i;
    if (idx < NN){ ro[idx] = run; cur[idx] = run; run += c[idx]; }
  }
  if (t == 0) ro[NN] = part[1023];
}

__global__ void k_fill2(const int* __restrict__ src_u, const int* __restrict__ dst_u,
                        const int* __restrict__ src_p, const int* __restrict__ dst_p,
                        int* __restrict__ cursor, int* __restrict__ col){ // col[2*NE]
  int i = blockIdx.x * blockDim.x + threadIdx.x;
  if (i < NE){
    int p = atomicAdd(&cursor[dst_u[i]], 1);
    col[p] = src_u[i];
  } else if (i < 2 * NE){
    int j = i - NE;
    int p = atomicAdd(&cursor[NN + dst_p[j]], 1);
    col[NE + p] = src_p[j];
  }
}

// ---------------- conv GEMM both towers: hsb = bf16(dinv * (x @ W)) ----------------
__global__ __launch_bounds__(256) void k_conv2(
        const unsigned short* __restrict__ Au, const unsigned short* __restrict__ Ap,
        const unsigned short* __restrict__ Wu, const unsigned short* __restrict__ Wp,
        const float* __restrict__ du, const float* __restrict__ dp,
        unsigned short* __restrict__ hu, unsigned short* __restrict__ hp){
  const unsigned short* Af = blockIdx.y ? Ap : Au;
  const unsigned short* Wf = blockIdx.y ? Wp : Wu;
  const float* dinv        = blockIdx.y ? dp : du;
  unsigned short* hsb      = blockIdx.y ? hp : hu;
  int gw = blockIdx.x * 4 + (threadIdx.x >> 6);
  int lane = threadIdx.x & 63;
  bool valid = gw < NRT;
  int R = valid ? gw : (NRT - 1);
  short8 a[4];
  #pragma unroll
  for (int kt = 0; kt < 4; kt++)
    a[kt] = *reinterpret_cast<const short8*>(Af + ((size_t)(R * 4 + kt) * 64 + lane) * 8);
  int fr = lane & 15, fq = lane >> 4;
  #pragma unroll
  for (int ct = 0; ct < 8; ct++){
    f32x4 acc = {0.f, 0.f, 0.f, 0.f};
    #pragma unroll
    for (int kt = 0; kt < 4; kt++){
      short8 b = *reinterpret_cast<const short8*>(Wf + ((size_t)(ct * 4 + kt) * 64 + lane) * 8);
      acc = __builtin_amdgcn_mfma_f32_16x16x32_bf16(a[kt], b, acc, 0, 0, 0);
    }
    if (valid){
      #pragma unroll
      for (int r = 0; r < 4; r++){
        int grow = R * 16 + fq * 4 + r;
        hsb[(size_t)grow * DD + ct * 16 + fr] = f2bf(dinv[grow] * acc[r]);
      }
    }
  }
}

// ---------------- aggregation both towers (bf16 hs) -> frag bf16, 4-deep MLP ----------------
__global__ void k_agg2(const unsigned short* __restrict__ hu, const unsigned short* __restrict__ hp,
                       const float* __restrict__ du, const float* __restrict__ dp,
                       const int* __restrict__ ro, const int* __restrict__ colb,
                       const float* __restrict__ bu, const float* __restrict__ bp,
                       unsigned short* __restrict__ xfu, unsigned short* __restrict__ xfp,
                       int KT, int toff_p){
  const int g = blockIdx.y;
  const unsigned short* hsb = g ? hp : hu;
  const float* dv   = g ? dp : du;
  const float* bias = g ? bp : bu;
  unsigned short* xf = g ? xfp : xfu;
  const int* row_off = ro + g * (NN + 1);
  const int* col     = colb + (size_t)g * NE;
  const int toff = g ? toff_p : 0;

  int node = blockIdx.x * blockDim.y + threadIdx.y;
  int tx = threadIdx.x;   // 0..15; dims tx*8..tx*8+7
  if (node >= NN) return;
  const short8* h8 = reinterpret_cast<const short8*>(hsb);
  float a[8];
  {
    short8 v = h8[(size_t)node * 16 + tx];
    #pragma unroll
    for (int j = 0; j < 8; j++) a[j] = bf2f((unsigned short)v[j]);
  }
  int s = row_off[node], e = row_off[node + 1];
  int i = s;
  for (; i + 3 < e; i += 4){
    short8 v0 = h8[(size_t)col[i] * 16 + tx];
    short8 v1 = h8[(size_t)col[i + 1] * 16 + tx];
    short8 v2 = h8[(size_t)col[i + 2] * 16 + tx];
    short8 v3 = h8[(size_t)col[i + 3] * 16 + tx];
    #pragma unroll
    for (int j = 0; j < 8; j++)
      a[j] += (bf2f((unsigned short)v0[j]) + bf2f((unsigned short)v1[j]))
            + (bf2f((unsigned short)v2[j]) + bf2f((unsigned short)v3[j]));
  }
  for (; i < e; i++){
    short8 v = h8[(size_t)col[i] * 16 + tx];
    #pragma unroll
    for (int j = 0; j < 8; j++) a[j] += bf2f((unsigned short)v[j]);
  }
  float dn = dv[node];
  short8 ov;
  #pragma unroll
  for (int j = 0; j < 8; j++)
    ov[j] = (short)f2bf(dn * a[j] + bias[tx * 8 + j]);
  size_t chunk = ((size_t)(node >> 4) * KT + toff + (tx >> 2)) * 64 + (tx & 3) * 16 + (node & 15);
  *reinterpret_cast<short8*>(xf + chunk * 8) = ov;
}

// ---------------- big GEMM v3: B-stationary, B-in-regs, A via LDS dbuf ----------------
// grid 474 = 79 col-panels x 6 row-range blocks, 2 blocks/CU.
// PASS 0: rowsum atomics (no stores). PASS 1: out = exp/rowsum, full-line nt stores.
template<int PASS>
__global__ __launch_bounds__(256, 2) void k_big(
    const unsigned short* __restrict__ Af, const unsigned short* __restrict__ Bf,
    const float* __restrict__ ob, float* __restrict__ rowsum, float* __restrict__ out){
  __shared__ unsigned short sA[2][16384];   // 2 x 32KB (one 64-row x 256-K tile)
  const int tid = threadIdx.x, lane = tid & 63, wid = tid >> 6;
  const int wm = wid >> 1, wn = wid & 1;
  const int fr = lane & 15, fq = lane >> 4;

  // bijective XCD chunking: 474 = 8*59 + 2
  const int orig = blockIdx.x;
  const int xcd = orig & 7, pos = orig >> 3;
  const int wgid = (xcd < 2 ? xcd * 60 : 120 + (xcd - 2) * 59) + pos;
  const int cp = wgid / 6, six = wgid - cp * 6;
  const int rt0 = six * 52 + (six < 2 ? six : 2);     // row-tile-of-64 start
  const int nrt = 52 + (six < 2 ? 1 : 0);             // 53,53,52,52,52,52 -> 314
  const int bct = cp * 8;

  // B regs: wave's 4 col-tiles x 8 k-tiles (128 VGPR)
  short8 breg[4][8];
  #pragma unroll
  for (int n = 0; n < 4; n++)
    #pragma unroll
    for (int kt = 0; kt < 8; kt++)
      breg[n][kt] = *reinterpret_cast<const short8*>(
          Bf + (((size_t)(bct + wn * 4 + n) * 8 + kt) * 64 + lane) * 8);

  float obv[4];
  #pragma unroll
  for (int n = 0; n < 4; n++){
    int gcol = cp * 128 + wn * 64 + n * 16 + fr;
    obv[n] = (gcol < NP) ? ob[gcol] : 0.f;
  }

#define STAGEA(buf, rt) do{                                                    \
    _Pragma("unroll")                                                          \
    for (int i_ = 0; i_ < 8; i_++){                                            \
      int c_ = i_ * 256 + tid;                                                 \
      gload_lds16(Af + ((size_t)(rt) * 2048 + c_) * 8, (void*)&sA[buf][c_ * 8]); \
    } }while(0)

  STAGEA(0, rt0);
  for (int t = 0; t < nrt; t++){
    const int p = t & 1;
    if (t + 1 < nrt){
      STAGEA(p ^ 1, rt0 + t + 1);
      asm volatile("s_waitcnt vmcnt(8)" ::: "memory");   // tile t landed, t+1 in flight
    } else {
      asm volatile("s_waitcnt vmcnt(0)" ::: "memory");
    }
    __builtin_amdgcn_s_barrier();

    f32x4 acc[2][4] = {};
    __builtin_amdgcn_s_setprio(1);
    #pragma unroll
    for (int m = 0; m < 2; m++)
      #pragma unroll
      for (int kt = 0; kt < 8; kt++){
        short8 a = *reinterpret_cast<const short8*>(
            &sA[p][(((wm * 2 + m) * 8 + kt) * 64 + lane) * 8]);
        #pragma unroll
        for (int n = 0; n < 4; n++)
          acc[m][n] = __builtin_amdgcn_mfma_f32_16x16x32_bf16(a, breg[n][kt], acc[m][n], 0, 0, 0);
      }
    __builtin_amdgcn_s_setprio(0);
    __builtin_amdgcn_s_barrier();

    const int rbase = (rt0 + t) * 64 + wm * 32;
    if (PASS == 0){
      #pragma unroll
      for (int m = 0; m < 2; m++)
        #pragma unroll
        for (int r = 0; r < 4; r++){
          const int grow = rbase + m * 16 + fq * 4 + r;
          float rs = 0.f;
          #pragma unroll
          for (int n = 0; n < 4; n++){
            const int gcol = cp * 128 + wn * 64 + n * 16 + fr;
            rs += (gcol < NP) ? __expf(acc[m][n][r] + obv[n]) : 0.f;
          }
          rs += __shfl_xor(rs, 1, 64);
          rs += __shfl_xor(rs, 2, 64);
          rs += __shfl_xor(rs, 4, 64);
          rs += __shfl_xor(rs, 8, 64);
          if (fr == 0 && grow < NN) atomicAdd(&rowsum[grow], rs);
        }
    } else {
      #pragma unroll
      for (int m = 0; m < 2; m++)
        #pragma unroll
        for (int r = 0; r < 4; r++){
          const int grow = rbase + m * 16 + fq * 4 + r;
          const bool rv = grow < NN;
          const float ri = rv ? 1.f / rowsum[grow] : 0.f;
          #pragma unroll
          for (int n = 0; n < 4; n++){
            const int gcol = cp * 128 + wn * 64 + n * 16 + fr;
            if (rv && gcol < NP)
              __builtin_nontemporal_store(ri * __expf(acc[m][n][r] + obv[n]),
                                          &out[(size_t)grow * NP + gcol]);
          }
        }
    }
  }
#undef STAGEA
}

// ---------------- host ----------------
extern "C" void kernel_launch(void* const* d_in, const int* in_sizes, int n_in,
                              void* d_out, int out_size, void* d_ws, size_t ws_size,
                              hipStream_t stream){
  const int*   user_ids = (const int*)d_in[0];
  const int*   prod_ids = (const int*)d_in[1];
  const int*   ei_u     = (const int*)d_in[2];
  const int*   ei_p     = (const int*)d_in[3];
  const float* utab     = (const float*)d_in[4];
  const float* ptab     = (const float*)d_in[5];
  const float* uW       = (const float*)d_in[6];
  const float* ub       = (const float*)d_in[7];
  const float* pW       = (const float*)d_in[8];
  const float* pb       = (const float*)d_in[9];
  const float* oW       = (const float*)d_in[10];
  const float* ob       = (const float*)d_in[11];
  float* out = (float*)d_out;
  (void)in_sizes; (void)n_in; (void)out_size; (void)ws_size;

  char* w = (char*)d_ws;
  size_t off = 0;
  auto alloc = [&](size_t bytes)->void*{
    void* p = w + off; off += (bytes + 255) & ~(size_t)255; return p;
  };
  int*   cnt    = (int*)alloc(2 * NN * 4);
  float* rowsum = (float*)alloc(NN * 4);
  float* dinv   = (float*)alloc(2 * NN * 4);     // [u | p]
  int*   ro     = (int*)alloc(2 * (NN + 1) * 4); // [u | p]
  int*   cur    = (int*)alloc(2 * NN * 4);
  int*   colb   = (int*)alloc((size_t)2 * NE * 4);
  unsigned short* xu_f  = (unsigned short*)alloc((size_t)NN * DD * 2);
  unsigned short* xp_f  = (unsigned short*)alloc((size_t)NN * DD * 2);
  unsigned short* xu2_f = (unsigned short*)alloc((size_t)NN * DD * 2);
  unsigned short* xp2_f = (unsigned short*)alloc((size_t)NN * DD * 2);
  unsigned short* comb_f= (unsigned short*)alloc((size_t)NRT_PAD * 8 * 64 * 8 * 2);
  unsigned short* hu    = (unsigned short*)alloc((size_t)NN * DD * 2);
  unsigned short* hp    = (unsigned short*)alloc((size_t)NN * DD * 2);
  unsigned short* WuF0 = (unsigned short*)alloc((size_t)DD * DD * 2);
  unsigned short* WuF1 = (unsigned short*)alloc((size_t)DD * DD * 2);
  unsigned short* WpF0 = (unsigned short*)alloc((size_t)DD * DD * 2);
  unsigned short* WpF1 = (unsigned short*)alloc((size_t)DD * DD * 2);
  unsigned short* WoF  = (unsigned short*)alloc((size_t)NCT_PAD * 8 * 64 * 8 * 2);

  hipMemsetAsync(cnt, 0, (2 * NN + NN) * 4, stream);             // cnt + rowsum
  hipMemsetAsync(comb_f + (size_t)NRT * 8 * 64 * 8, 0,
                 (size_t)(NRT_PAD - NRT) * 8 * 64 * 8 * 2, stream);  // pad rows only

  const int* src_u = ei_u;  const int* dst_u = ei_u + NE;
  const int* src_p = ei_p;  const int* dst_p = ei_p + NE;

  // mega-prologue: count + gathers + all weight packers
  k_prep<<<PREP_NWG, 256, 0, stream>>>(dst_u, dst_p, cnt,
                                       utab, user_ids, ptab, prod_ids, xu_f, xp_f,
                                       uW, pW, WuF0, WuF1, WpF0, WpF1, oW, WoF);
  k_scan2<<<2, 1024, 0, stream>>>(cnt, ro, cur, dinv);
  k_fill2<<<(2 * NE + 255) / 256, 256, 0, stream>>>(src_u, dst_u, src_p, dst_p, cur, colb);

  const int convGrid = (NRT + 3) / 4;   // 313
  dim3 aggBlk(16, 16);
  const int aggGrid = (NN + 15) / 16;

  // layer 1 (both towers per launch)
  k_conv2<<<dim3(convGrid, 2), 256, 0, stream>>>(xu_f, xp_f, WuF0, WpF0,
                                                 dinv, dinv + NN, hu, hp);
  k_agg2<<<dim3(aggGrid, 2), aggBlk, 0, stream>>>(hu, hp, dinv, dinv + NN, ro, colb,
                                                  ub, pb, xu2_f, xp2_f, 4, 0);
  // layer 2 -> comb fragments (user ktiles 0..3, product ktiles 4..7)
  k_conv2<<<dim3(convGrid, 2), 256, 0, stream>>>(xu2_f, xp2_f, WuF1, WpF1,
                                                 dinv, dinv + NN, hu, hp);
  k_agg2<<<dim3(aggGrid, 2), aggBlk, 0, stream>>>(hu, hp, dinv, dinv + NN, ro, colb,
                                                  ub + DD, pb + DD, comb_f, comb_f, 8, 4);

  // two-pass recompute softmax GEMM (B-stationary)
  k_big<0><<<NWG_BIG, 256, 0, stream>>>(comb_f, WoF, ob, rowsum, out);
  k_big<1><<<NWG_BIG, 256, 0, stream>>>(comb_f, WoF, ob, rowsum, out);
}